// Round 5
// baseline (230.992 us; speedup 1.0000x reference)
//
#include <hip/hip_runtime.h>

#define NBATCH 4
#define DDIM   256
#define NN     4096
#define MM     4096
#define NCHUNK 8          // m-chunks (split-K across workgroups)
#define MCHUNK 512        // m per chunk
#define LOG2E  1.44269504088896340736f

using half8   = __attribute__((ext_vector_type(8))) _Float16;
using floatx4 = __attribute__((ext_vector_type(4))) float;

// Fragment-ordered fp16 layout (per batch): frag(blk, ds, oct, l15) is a half8
// covering point p = blk*16 + l15, dims d = ds*32 + oct*8 .. +7, at half8 index
// ((blk*8 + ds)*4 + oct)*16 + l15.  A wave reading (l15 fast, oct=quad) gets a
// fully-coalesced 1 KB global load per (blk, ds) — MFMA-ready, no LDS staging.

// ---------- prep: emb[b][d][n] fp32 -> fragment-ordered fp16; fused yy + Vt ----------
__global__ __launch_bounds__(256) void k_prep(const float* __restrict__ src_emb,
                                              const float* __restrict__ tgt_emb,
                                              const float* __restrict__ tgt,
                                              _Float16* __restrict__ Qf,
                                              _Float16* __restrict__ Kf,
                                              float* __restrict__ yyS,
                                              float4* __restrict__ Vt) {
    __shared__ float psum[4][64];
    int i = blockIdx.x;                            // 512 = xcd(8) x j(64)
    int xcd = i & 7, j = i >> 3;
    int b = xcd >> 1, nhalf = xcd & 1;             // matches flash's XCD mapping
    int tensor = j & 1, sub = j >> 1;              // sub 0..31
    int n0 = nhalf * 2048 + sub * 64;
    const float* in = tensor ? tgt_emb : src_emb;
    _Float16* outp  = tensor ? Kf : Qf;
    const float scale = tensor ? 1.0f : 2.0f * LOG2E;   // fold 2*log2e into Q
    int t = threadIdx.x, w = t >> 6, ln = t & 63;
    const float* ib = in + (size_t)b * DDIM * NN + n0 + ln;
    _Float16* ob = outp + (size_t)b * NN * 32 * 8;      // batch-b fragment space
    int blk = (n0 + ln) >> 4, l15 = ln & 15;
    float ss = 0.f;
#pragma unroll
    for (int h = 0; h < 2; h++) {                  // wave w covers ds in {w, w+4}
        int ds = w + h * 4;
#pragma unroll
        for (int oct = 0; oct < 4; oct++) {
            half8 v;
#pragma unroll
            for (int k = 0; k < 8; k++) {
                float f = ib[(size_t)(ds * 32 + oct * 8 + k) * NN];  // 256B/wave coalesced
                ss = fmaf(f, f, ss);
                v[k] = (_Float16)(f * scale);
            }
            *(half8*)(ob + ((((size_t)blk * 8 + ds) * 4 + oct) * 16 + l15) * 8) = v;
        }
    }
    if (tensor) psum[w][ln] = ss;
    __syncthreads();
    if (tensor) {
        if (t < 64) {
            float s = psum[0][t] + psum[1][t] + psum[2][t] + psum[3][t];
            yyS[b * MM + n0 + t] = s * (-LOG2E);   // pre-negated, exp2-domain
        } else if (t < 128) {
            int m = n0 + (t - 64);
            const float* tp = tgt + (size_t)b * 3 * MM + m;
            Vt[(size_t)b * MM + m] = make_float4(tp[0], tp[MM], tp[2 * MM], 1.0f);
        }
    }
}

// ---------- flash: barrier-free K-loop, direct fragment loads from L2 ----------
__global__ __launch_bounds__(256, 3) void k_flash(const _Float16* __restrict__ Qf,
                                                  const _Float16* __restrict__ Kf,
                                                  const float* __restrict__ yyS,
                                                  const float4* __restrict__ Vt,
                                                  float4* __restrict__ Opart,
                                                  float* __restrict__ Mpart) {
    __shared__ floatx4 vtt[MCHUNK];                // 8 KB: {v0,v1,v2,1} per chunk-m
    __shared__ floatx4 yyt[MCHUNK / 4];            // 2 KB

    int i = blockIdx.x, t = threadIdx.x;           // grid 1024 = xcd(8) x j(128)
    int xcd = i & 7, j = i >> 3;
    int b = xcd >> 1, nhalf = xcd & 1;             // per-XCD: K[b] (2MB) L2-resident
    int chunk = j & 7, ntile = nhalf * 16 + (j >> 3);

    int wave = t >> 6, lane = t & 63, quad = lane >> 4, l15 = lane & 15;
    int m0 = chunk * MCHUNK;

    // stage V + yy for the whole chunk ONCE (the only barrier in this kernel)
    {
        const float4* vb = Vt + (size_t)b * MM + m0;
        for (int r = t; r < MCHUNK; r += 256) {
            float4 g = vb[r];
            vtt[r] = (floatx4){g.x, g.y, g.z, g.w};
        }
        const floatx4* yb = (const floatx4*)(yyS + (size_t)b * MM + m0);
        for (int r = t; r < MCHUNK / 4; r += 256) yyt[r] = yb[r];
    }

    // Q fragments: 32 n x 256 d per wave, coalesced 1 KB loads, L2-hot
    int nblk0 = ntile * 8 + wave * 2;
    const half8* qp = (const half8*)Qf + (size_t)b * NN * 32;
    half8 qf[2][8];
#pragma unroll
    for (int nb = 0; nb < 2; nb++)
#pragma unroll
        for (int ds = 0; ds < 8; ds++)
            qf[nb][ds] = qp[(((size_t)(nblk0 + nb) * 8 + ds) * 4 + quad) * 16 + l15];

    const half8* kp = (const half8*)Kf + (size_t)b * NN * 32;

    const floatx4 z4 = {0.f, 0.f, 0.f, 0.f};
    floatx4 o[2] = {z4, z4};                       // per-quad partial {o0,o1,o2,denom}
    float mr[2] = {-__builtin_inff(), -__builtin_inff()};

    __syncthreads();

    for (int mt = 0; mt < MCHUNK / 64; mt++) {     // 64-m tiles, NO barriers
        int mblk0 = chunk * 32 + mt * 4;

        // A-fragments for the whole tile: 32 coalesced 1 KB loads (L1/L2-hot)
        half8 a[4][8];
#pragma unroll
        for (int mb = 0; mb < 4; mb++)
#pragma unroll
            for (int ds = 0; ds < 8; ds++)
                a[mb][ds] = kp[(((size_t)(mblk0 + mb) * 8 + ds) * 4 + quad) * 16 + l15];

        floatx4 acc[2][4];
#pragma unroll
        for (int nb = 0; nb < 2; nb++)
#pragma unroll
            for (int mb = 0; mb < 4; mb++) acc[nb][mb] = z4;
#pragma unroll
        for (int ds = 0; ds < 8; ds++)
#pragma unroll
            for (int nb = 0; nb < 2; nb++)
#pragma unroll
                for (int mb = 0; mb < 4; mb++)
                    acc[nb][mb] = __builtin_amdgcn_mfma_f32_16x16x32_f16(a[mb][ds], qf[nb][ds], acc[nb][mb], 0, 0, 0);

        // online softmax (exp2 domain), per-quad partial — no cross-lane ops in loop
#pragma unroll
        for (int nb = 0; nb < 2; nb++) {
#pragma unroll
            for (int mb = 0; mb < 4; mb++) acc[nb][mb] = acc[nb][mb] + yyt[mt * 16 + mb * 4 + quad];
            floatx4 mx = __builtin_elementwise_max(
                __builtin_elementwise_max(acc[nb][0], acc[nb][1]),
                __builtin_elementwise_max(acc[nb][2], acc[nb][3]));
            float tm = fmaxf(fmaxf(mx[0], mx[1]), fmaxf(mx[2], mx[3]));
            float mn = fmaxf(mr[nb], tm);
            float al = __builtin_amdgcn_exp2f(mr[nb] - mn);
            mr[nb] = mn;
            o[nb] = o[nb] * al;
            floatx4 mnv = {mn, mn, mn, mn};
#pragma unroll
            for (int mb = 0; mb < 4; mb++) acc[nb][mb] = acc[nb][mb] - mnv;
        }
        // exp + PV (V broadcast from LDS, loaded once per kernel)
#pragma unroll
        for (int mb = 0; mb < 4; mb++) {
            floatx4 vr[4];
#pragma unroll
            for (int r = 0; r < 4; r++) vr[r] = vtt[mt * 64 + mb * 16 + quad * 4 + r];
#pragma unroll
            for (int nb = 0; nb < 2; nb++)
#pragma unroll
                for (int r = 0; r < 4; r++) {
                    float p = __builtin_amdgcn_exp2f(acc[nb][mb][r]);
                    o[nb] = o[nb] + p * vr[r];
                }
        }
    }

    // merge the 4 per-quad partial softmaxes (once per kernel)
#pragma unroll
    for (int nb = 0; nb < 2; nb++) {
        float mq = mr[nb];
        float ma = fmaxf(mq, __shfl_xor(mq, 16, 64));
        ma = fmaxf(ma, __shfl_xor(ma, 32, 64));
        float wgt = __builtin_amdgcn_exp2f(mq - ma);
        floatx4 ow = o[nb] * wgt;
#pragma unroll
        for (int c = 0; c < 4; c++) {
            float v = ow[c];
            v += __shfl_xor(v, 16, 64);
            v += __shfl_xor(v, 32, 64);
            ow[c] = v;
        }
        if (quad == 0) {
            int n = (nblk0 + nb) * 16 + l15;
            size_t idx = (size_t)(chunk * NBATCH + b) * NN + n;
            Opart[idx] = make_float4(ow[0], ow[1], ow[2], ow[3]);
            Mpart[idx] = ma;
        }
    }
}

// ---------- combine the 8 m-chunk partials per (b,n) ----------
__global__ __launch_bounds__(128) void k_combine(const float4* __restrict__ Opart,
                                                 const float* __restrict__ Mpart,
                                                 float* __restrict__ out) {
    int idx = blockIdx.x * 128 + threadIdx.x;      // b*NN + n
    int b = idx >> 12, n = idx & (NN - 1);
    float mstar = -__builtin_inff();
#pragma unroll
    for (int j = 0; j < NCHUNK; j++)
        mstar = fmaxf(mstar, Mpart[(size_t)(j * NBATCH + b) * NN + n]);
    float o0 = 0.f, o1 = 0.f, o2 = 0.f, l = 0.f;
#pragma unroll
    for (int j = 0; j < NCHUNK; j++) {
        size_t id = (size_t)(j * NBATCH + b) * NN + n;
        float w = __builtin_amdgcn_exp2f(Mpart[id] - mstar);
        float4 P = Opart[id];
        o0 = fmaf(w, P.x, o0); o1 = fmaf(w, P.y, o1);
        o2 = fmaf(w, P.z, o2); l  = fmaf(w, P.w, l);
    }
    out[(size_t)(b * 3 + 0) * NN + n] = o0 / l;
    out[(size_t)(b * 3 + 1) * NN + n] = o1 / l;
    out[(size_t)(b * 3 + 2) * NN + n] = o2 / l;
}

extern "C" void kernel_launch(void* const* d_in, const int* in_sizes, int n_in,
                              void* d_out, int out_size, void* d_ws, size_t ws_size,
                              hipStream_t stream) {
    const float* tgt     = (const float*)d_in[1];
    const float* src_emb = (const float*)d_in[2];
    const float* tgt_emb = (const float*)d_in[3];
    float* out = (float*)d_out;

    char* ws = (char*)d_ws;
    // ws: Qf 8.39M | Kf 8.39M | yyS 64K | Vt 256K | Opart 2M | Mpart 512K  (~19.7 MB)
    _Float16* Qf  = (_Float16*)(ws);
    _Float16* Kf  = (_Float16*)(ws + 8388608);
    float*    yyS = (float*)   (ws + 16777216);
    float4*   Vt  = (float4*)  (ws + 16842752);
    float4*   Op  = (float4*)  (ws + 17104896);
    float*    Mp  = (float*)   (ws + 19202048);

    hipLaunchKernelGGL(k_prep,    dim3(512),  dim3(256), 0, stream,
                       src_emb, tgt_emb, tgt, Qf, Kf, yyS, Vt);
    hipLaunchKernelGGL(k_flash,   dim3(1024), dim3(256), 0, stream, Qf, Kf, yyS, Vt, Op, Mp);
    hipLaunchKernelGGL(k_combine, dim3(128),  dim3(128), 0, stream, Op, Mp, out);
}

// Round 6
// 155.465 us; speedup vs baseline: 1.4858x; 1.4858x over previous
//
#include <hip/hip_runtime.h>

#define NBATCH 4
#define DDIM   256
#define NN     4096
#define MM     4096
#define NCHUNK 8          // m-chunks (split-K across workgroups)
#define MCHUNK 512        // m per chunk
#define MTILE  32         // m per LDS tile (16 tiles/chunk)
#define LOG2E  1.44269504088896340736f

using half8   = __attribute__((ext_vector_type(8))) _Float16;
using floatx4 = __attribute__((ext_vector_type(4))) float;

// ---------- prep: emb[b][d][n] fp32 -> row-major [b][n][d] fp16; fused yy + Vt ----------
__global__ __launch_bounds__(256) void k_prep(const float* __restrict__ src_emb,
                                              const float* __restrict__ tgt_emb,
                                              const float* __restrict__ tgt,
                                              _Float16* __restrict__ Qh,
                                              _Float16* __restrict__ Kh,
                                              float* __restrict__ yyS,
                                              float4* __restrict__ Vt) {
    __shared__ float psum[4][64];
    int i = blockIdx.x;                            // 512 = xcd(8) x j(64)
    int xcd = i & 7, j = i >> 3;
    int b = xcd >> 1, nhalf = xcd & 1;             // match flash XCD mapping (L2 locality)
    int tensor = j & 1, sub = j >> 1;              // 32 subs x 64 points
    int n0 = nhalf * 2048 + sub * 64;
    const float* in = tensor ? tgt_emb : src_emb;
    _Float16* outp  = tensor ? Kh : Qh;
    const float scale = tensor ? 1.0f : 2.0f * LOG2E;   // fold 2*log2e into Q
    int t = threadIdx.x, w = t >> 6, ln = t & 63;
    const float* ib = in + (size_t)b * DDIM * NN + n0 + ln;
    _Float16* op = outp + (size_t)(b * NN + n0 + ln) * DDIM;
    float ss = 0.f;
#pragma unroll
    for (int itr = 0; itr < 8; itr++) {
        int dg = w + itr * 4;                      // d-group [0,32)
        half8 h;
#pragma unroll
        for (int k = 0; k < 8; k++) {
            float f = ib[(size_t)(dg * 8 + k) * NN];   // coalesced: 64 lanes x 4B
            ss = fmaf(f, f, ss);
            h[k] = (_Float16)(f * scale);
        }
        *(half8*)(op + dg * 8) = h;
    }
    if (tensor) psum[w][ln] = ss;
    __syncthreads();
    if (tensor) {
        if (t < 64) {
            float s = psum[0][t] + psum[1][t] + psum[2][t] + psum[3][t];
            yyS[b * MM + n0 + t] = s * (-LOG2E);   // pre-negated, exp2-domain
        } else if (t < 128) {
            int m = n0 + (t - 64);
            const float* tp = tgt + (size_t)b * 3 * MM + m;
            Vt[(size_t)b * MM + m] = make_float4(tp[0], tp[MM], tp[2 * MM], 1.0f);
        }
    }
}

// ---------- flash: DMA-staged K, dbuf, 1 barrier/tile, per-quad softmax ----------
__global__ __launch_bounds__(256) void k_flash(const _Float16* __restrict__ Qh,
                                               const _Float16* __restrict__ Kh,
                                               const float* __restrict__ yyS,
                                               const float4* __restrict__ Vt,
                                               float4* __restrict__ Opart,
                                               float* __restrict__ Mpart) {
    __shared__ __align__(16) _Float16 Kt[2][MTILE * DDIM];   // 2 x 16 KB
    __shared__ floatx4 vtt[MCHUNK];                          // 8 KB {v0,v1,v2,1}
    __shared__ floatx4 yyt[MCHUNK / 4];                      // 2 KB

    int i = blockIdx.x, t = threadIdx.x;           // grid 512 = xcd(8) x j(64)
    int xcd = i & 7, j = i >> 3;
    int b = xcd >> 1, nhalf = xcd & 1;             // per-XCD K slice L2-resident
    int chunk = j & 7, ntile = nhalf * 8 + (j >> 3);

    int wave = t >> 6, lane = t & 63, quad = lane >> 4, l15 = lane & 15;
    int n0 = ntile * 256 + wave * 64;
    int m0 = chunk * MCHUNK;

    const _Float16* kp = Kh + (size_t)b * MM * DDIM;
    int dg = lane & 31, rh = lane >> 5;
    // async DMA: one 32x256 fp16 K-tile; zero VGPR staging cost
    auto stage = [&](int mt) {
        const _Float16* gb = kp + (size_t)(m0 + mt * MTILE) * DDIM;
        _Float16* lb = &Kt[mt & 1][0];
#pragma unroll
        for (int it = 0; it < 4; it++) {
            int row = wave * 8 + it * 2 + rh;
            __builtin_amdgcn_global_load_lds(
                (const __attribute__((address_space(1))) uint32_t*)(const void*)
                    (gb + (size_t)row * DDIM + dg * 8),
                (__attribute__((address_space(3))) uint32_t*)(void*)
                    (lb + (wave * 8 + it * 2) * DDIM),
                16, 0, 0);
        }
    };

    stage(0);                                      // K-tile 0 in flight

    // whole-chunk V + yy staged ONCE (no global loads inside the K-loop)
    {
        const float4* vb = Vt + (size_t)b * MM + m0;
        for (int r = t; r < MCHUNK; r += 256) {
            float4 g = vb[r];
            vtt[r] = (floatx4){g.x, g.y, g.z, g.w};
        }
        const floatx4* yb = (const floatx4*)(yyS + (size_t)b * MM + m0);
        if (t < MCHUNK / 4) yyt[t] = yb[t];
    }

    // persistent Q fragments: 64n x 256d per wave (128 VGPRs), L2-hot
    const _Float16* qp = Qh + (size_t)b * NN * DDIM;
    half8 qf[4][8];
#pragma unroll
    for (int nb = 0; nb < 4; nb++) {
        int n = n0 + nb * 16 + l15;
#pragma unroll
        for (int ds = 0; ds < 8; ds++)
            qf[nb][ds] = *(const half8*)(qp + (size_t)n * DDIM + (ds * 4 + quad) * 8);
    }

    const floatx4 z4 = {0.f, 0.f, 0.f, 0.f};
    floatx4 o[4] = {z4, z4, z4, z4};               // per-quad partial {o0,o1,o2,denom}
    float mr[4];
#pragma unroll
    for (int nb = 0; nb < 4; nb++) mr[nb] = -__builtin_inff();

    for (int mt = 0; mt < MCHUNK / MTILE; mt++) {
        __syncthreads();                           // drains DMA(mt) (issued one tile ago)
        if (mt + 1 < MCHUNK / MTILE) stage(mt + 1);     // prefetch overlaps this tile

        const _Float16* Kb = &Kt[mt & 1][0];
        floatx4 acc[4][2];
#pragma unroll
        for (int nb = 0; nb < 4; nb++) { acc[nb][0] = z4; acc[nb][1] = z4; }
#pragma unroll
        for (int ds = 0; ds < 8; ds++) {           // a live-set: 2 half8 = 8 VGPRs
            half8 a0 = *(const half8*)(Kb + (size_t)l15 * DDIM + (ds * 4 + quad) * 8);
            half8 a1 = *(const half8*)(Kb + (size_t)(16 + l15) * DDIM + (ds * 4 + quad) * 8);
#pragma unroll
            for (int nb = 0; nb < 4; nb++) {
                acc[nb][0] = __builtin_amdgcn_mfma_f32_16x16x32_f16(a0, qf[nb][ds], acc[nb][0], 0, 0, 0);
                acc[nb][1] = __builtin_amdgcn_mfma_f32_16x16x32_f16(a1, qf[nb][ds], acc[nb][1], 0, 0, 0);
            }
        }

        // per-quad online softmax (exp2 domain); quad owns m = mt*32 + mb*16 + quad*4 + r
        floatx4 yv0 = yyt[mt * 8 + quad];
        floatx4 yv1 = yyt[mt * 8 + 4 + quad];
#pragma unroll
        for (int nb = 0; nb < 4; nb++) {
            acc[nb][0] = acc[nb][0] + yv0;
            acc[nb][1] = acc[nb][1] + yv1;
            floatx4 mx = __builtin_elementwise_max(acc[nb][0], acc[nb][1]);
            float tm = fmaxf(fmaxf(mx[0], mx[1]), fmaxf(mx[2], mx[3]));
            float mn = fmaxf(mr[nb], tm);
            float al = __builtin_amdgcn_exp2f(mr[nb] - mn);
            mr[nb] = mn;
            o[nb] = o[nb] * al;
            floatx4 mnv = {mn, mn, mn, mn};
            acc[nb][0] = acc[nb][0] - mnv;
            acc[nb][1] = acc[nb][1] - mnv;
        }
#pragma unroll
        for (int mb = 0; mb < 2; mb++) {
            floatx4 vr[4];
#pragma unroll
            for (int r = 0; r < 4; r++) vr[r] = vtt[mt * 32 + mb * 16 + quad * 4 + r];
#pragma unroll
            for (int nb = 0; nb < 4; nb++)
#pragma unroll
                for (int r = 0; r < 4; r++) {
                    float p = __builtin_amdgcn_exp2f(acc[nb][mb][r]);
                    o[nb] = o[nb] + p * vr[r];
                }
        }
    }

    // merge the 4 per-quad partial softmaxes (once per kernel)
#pragma unroll
    for (int nb = 0; nb < 4; nb++) {
        float mq = mr[nb];
        float ma = fmaxf(mq, __shfl_xor(mq, 16, 64));
        ma = fmaxf(ma, __shfl_xor(ma, 32, 64));
        float wgt = __builtin_amdgcn_exp2f(mq - ma);
        floatx4 ow = o[nb] * wgt;
#pragma unroll
        for (int c = 0; c < 4; c++) {
            float v = ow[c];
            v += __shfl_xor(v, 16, 64);
            v += __shfl_xor(v, 32, 64);
            ow[c] = v;
        }
        if (quad == 0) {
            int n = n0 + nb * 16 + l15;
            size_t idx = (size_t)(chunk * NBATCH + b) * NN + n;
            Opart[idx] = make_float4(ow[0], ow[1], ow[2], ow[3]);
            Mpart[idx] = ma;
        }
    }
}

// ---------- combine the 8 m-chunk partials per (b,n) ----------
__global__ __launch_bounds__(128) void k_combine(const float4* __restrict__ Opart,
                                                 const float* __restrict__ Mpart,
                                                 float* __restrict__ out) {
    int idx = blockIdx.x * 128 + threadIdx.x;      // b*NN + n
    int b = idx >> 12, n = idx & (NN - 1);
    float mstar = -__builtin_inff();
#pragma unroll
    for (int j = 0; j < NCHUNK; j++)
        mstar = fmaxf(mstar, Mpart[(size_t)(j * NBATCH + b) * NN + n]);
    float o0 = 0.f, o1 = 0.f, o2 = 0.f, l = 0.f;
#pragma unroll
    for (int j = 0; j < NCHUNK; j++) {
        size_t id = (size_t)(j * NBATCH + b) * NN + n;
        float w = __builtin_amdgcn_exp2f(Mpart[id] - mstar);
        float4 P = Opart[id];
        o0 = fmaf(w, P.x, o0); o1 = fmaf(w, P.y, o1);
        o2 = fmaf(w, P.z, o2); l  = fmaf(w, P.w, l);
    }
    out[(size_t)(b * 3 + 0) * NN + n] = o0 / l;
    out[(size_t)(b * 3 + 1) * NN + n] = o1 / l;
    out[(size_t)(b * 3 + 2) * NN + n] = o2 / l;
}

extern "C" void kernel_launch(void* const* d_in, const int* in_sizes, int n_in,
                              void* d_out, int out_size, void* d_ws, size_t ws_size,
                              hipStream_t stream) {
    const float* tgt     = (const float*)d_in[1];
    const float* src_emb = (const float*)d_in[2];
    const float* tgt_emb = (const float*)d_in[3];
    float* out = (float*)d_out;

    char* ws = (char*)d_ws;
    // ws: Qh 8.39M | Kh 8.39M | yyS 64K | Vt 256K | Opart 2M | Mpart 512K  (~19.7 MB)
    _Float16* Qh  = (_Float16*)(ws);
    _Float16* Kh  = (_Float16*)(ws + 8388608);
    float*    yyS = (float*)   (ws + 16777216);
    float4*   Vt  = (float4*)  (ws + 16842752);
    float4*   Op  = (float4*)  (ws + 17104896);
    float*    Mp  = (float*)   (ws + 19202048);

    hipLaunchKernelGGL(k_prep,    dim3(512), dim3(256), 0, stream,
                       src_emb, tgt_emb, tgt, Qh, Kh, yyS, Vt);
    hipLaunchKernelGGL(k_flash,   dim3(512), dim3(256), 0, stream, Qh, Kh, yyS, Vt, Op, Mp);
    hipLaunchKernelGGL(k_combine, dim3(128), dim3(128), 0, stream, Op, Mp, out);
}

// Round 7
// 133.447 us; speedup vs baseline: 1.7310x; 1.1650x over previous
//
#include <hip/hip_runtime.h>

#define NBATCH 4
#define DDIM   256
#define NN     4096
#define MM     4096
#define NCHUNK 8          // m-chunks (split-K across workgroups)
#define MCHUNK 512        // m per chunk
#define MTILE  64         // m per LDS tile (8 tiles/chunk)
#define PAIRB  1040       // LDS bytes per K row-pair: 1024 data + 16 pad (bank rotate)
#define SUBB   (32 * PAIRB)   // one 64-row sub-buffer = 33280 B
#define LOG2E  1.44269504088896340736f

using half8   = __attribute__((ext_vector_type(8))) _Float16;
using floatx4 = __attribute__((ext_vector_type(4))) float;

// ---------- prep: emb[b][d][n] fp32 -> row-major [b][n][d] fp16; fused yy + Vt ----------
__global__ __launch_bounds__(256) void k_prep(const float* __restrict__ src_emb,
                                              const float* __restrict__ tgt_emb,
                                              const float* __restrict__ tgt,
                                              _Float16* __restrict__ Qh,
                                              _Float16* __restrict__ Kh,
                                              float* __restrict__ yyS,
                                              float4* __restrict__ Vt) {
    __shared__ float psum[4][64];
    int i = blockIdx.x;                            // 512 = xcd(8) x j(64)
    int xcd = i & 7, j = i >> 3;
    int b = xcd >> 1, nhalf = xcd & 1;             // match flash XCD mapping (L2 locality)
    int tensor = j & 1, sub = j >> 1;              // 32 subs x 64 points
    int n0 = nhalf * 2048 + sub * 64;
    const float* in = tensor ? tgt_emb : src_emb;
    _Float16* outp  = tensor ? Kh : Qh;
    const float scale = tensor ? 1.0f : 2.0f * LOG2E;   // fold 2*log2e into Q
    int t = threadIdx.x, w = t >> 6, ln = t & 63;
    const float* ib = in + (size_t)b * DDIM * NN + n0 + ln;
    _Float16* op = outp + (size_t)(b * NN + n0 + ln) * DDIM;
    float ss = 0.f;
#pragma unroll
    for (int itr = 0; itr < 8; itr++) {
        int dg = w + itr * 4;                      // d-group [0,32)
        half8 h;
#pragma unroll
        for (int k = 0; k < 8; k++) {
            float f = ib[(size_t)(dg * 8 + k) * NN];   // coalesced: 64 lanes x 4B
            ss = fmaf(f, f, ss);
            h[k] = (_Float16)(f * scale);
        }
        *(half8*)(op + dg * 8) = h;
    }
    if (tensor) psum[w][ln] = ss;
    __syncthreads();
    if (tensor) {
        if (t < 64) {
            float s = psum[0][t] + psum[1][t] + psum[2][t] + psum[3][t];
            yyS[b * MM + n0 + t] = s * (-LOG2E);   // pre-negated, exp2-domain
        } else if (t < 128) {
            int m = n0 + (t - 64);
            const float* tp = tgt + (size_t)b * 3 * MM + m;
            Vt[(size_t)b * MM + m] = make_float4(tp[0], tp[MM], tp[2 * MM], 1.0f);
        }
    }
}

// ---------- flash: DMA dbuf K (pair-padded LDS), 1 barrier/tile, per-quad softmax ----------
__global__ __launch_bounds__(256, 2) void k_flash(const _Float16* __restrict__ Qh,
                                                  const _Float16* __restrict__ Kh,
                                                  const float* __restrict__ yyS,
                                                  const float4* __restrict__ Vt,
                                                  float4* __restrict__ Opart,
                                                  float* __restrict__ Mpart) {
    __shared__ __align__(16) char Kt[2 * SUBB];    // 65 KB: 2 sub-buffers, pair-padded
    __shared__ floatx4 vtt[MCHUNK];                // 8 KB {v0,v1,v2,1}
    __shared__ floatx4 yyt[MCHUNK / 4];            // 2 KB

    int i = blockIdx.x, t = threadIdx.x;           // grid 512 = xcd(8) x j(64)
    int xcd = i & 7, j = i >> 3;
    int b = xcd >> 1, nhalf = xcd & 1;             // per-XCD K slice L2-resident
    int chunk = j & 7, ntile = nhalf * 8 + (j >> 3);

    int wave = t >> 6, lane = t & 63, quad = lane >> 4, l15 = lane & 15;
    int n0 = ntile * 256 + wave * 64;
    int m0 = chunk * MCHUNK;

    const _Float16* kp = Kh + (size_t)b * MM * DDIM;
    int dg = lane & 31, rh = lane >> 5;
    // async DMA of one 64x256 fp16 K-tile; dest = pair-padded (1040B/pair), 1024B per instr
    auto stage = [&](int mt) {
        const _Float16* gb = kp + (size_t)(m0 + mt * MTILE) * DDIM;
        char* lb = &Kt[(mt & 1) * SUBB];
#pragma unroll
        for (int it = 0; it < 8; it++) {
            int pr = wave * 8 + it;                // row-pair index [0,32)
            __builtin_amdgcn_global_load_lds(
                (const __attribute__((address_space(1))) uint32_t*)(const void*)
                    (gb + (size_t)(pr * 2 + rh) * DDIM + dg * 8),
                (__attribute__((address_space(3))) uint32_t*)(void*)
                    (lb + pr * PAIRB),
                16, 0, 0);
        }
    };

    stage(0);                                      // K-tile 0 in flight first

    // whole-chunk V + yy staged ONCE (no global loads inside the K-loop)
    {
        const float4* vb = Vt + (size_t)b * MM + m0;
        for (int r = t; r < MCHUNK; r += 256) {
            float4 g = vb[r];
            vtt[r] = (floatx4){g.x, g.y, g.z, g.w};
        }
        const floatx4* yb = (const floatx4*)(yyS + (size_t)b * MM + m0);
        if (t < MCHUNK / 4) yyt[t] = yb[t];
    }

    // persistent Q fragments: 64n x 256d per wave (128 VGPRs), L2-hot
    const _Float16* qp = Qh + (size_t)b * NN * DDIM;
    half8 qf[4][8];
#pragma unroll
    for (int nb = 0; nb < 4; nb++) {
        int n = n0 + nb * 16 + l15;
#pragma unroll
        for (int ds = 0; ds < 8; ds++)
            qf[nb][ds] = *(const half8*)(qp + (size_t)n * DDIM + (ds * 4 + quad) * 8);
    }

    const floatx4 z4 = {0.f, 0.f, 0.f, 0.f};
    floatx4 o[4] = {z4, z4, z4, z4};               // per-quad partial {o0,o1,o2,denom}
    float mr[4];
#pragma unroll
    for (int nb = 0; nb < 4; nb++) mr[nb] = -__builtin_inff();

    for (int mt = 0; mt < MCHUNK / MTILE; mt++) {
        __syncthreads();                           // drains DMA(mt) (issued one tile ago)
        if (mt + 1 < MCHUNK / MTILE) stage(mt + 1);     // prefetch flies over this tile

        const char* Kb = &Kt[(mt & 1) * SUBB];
#pragma unroll
        for (int mb = 0; mb < 4; mb++) {           // 16-m block; quad owns m=..+quad*4+r
            // A-fragments: pair-padded addressing -> 2-way banks (free)
            half8 a[8];
            {
                int rho = mb * 16 + l15;
                const char* rb = Kb + (rho >> 1) * PAIRB + (rho & 1) * 512 + quad * 16;
#pragma unroll
                for (int ds = 0; ds < 8; ds++) a[ds] = *(const half8*)(rb + ds * 64);
            }
            floatx4 acc[4] = {z4, z4, z4, z4};
#pragma unroll
            for (int ds = 0; ds < 8; ds++)
#pragma unroll
                for (int nb = 0; nb < 4; nb++)
                    acc[nb] = __builtin_amdgcn_mfma_f32_16x16x32_f16(a[ds], qf[nb][ds], acc[nb], 0, 0, 0);

            // per-quad online softmax (exp2 domain) + PV
            floatx4 yv = yyt[mt * 16 + mb * 4 + quad];
            floatx4 vr[4];
#pragma unroll
            for (int r = 0; r < 4; r++) vr[r] = vtt[mt * MTILE + mb * 16 + quad * 4 + r];
#pragma unroll
            for (int nb = 0; nb < 4; nb++) {
                acc[nb] = acc[nb] + yv;
                float tm = fmaxf(fmaxf(acc[nb][0], acc[nb][1]), fmaxf(acc[nb][2], acc[nb][3]));
                float mn = fmaxf(mr[nb], tm);
                float al = __builtin_amdgcn_exp2f(mr[nb] - mn);
                mr[nb] = mn;
                o[nb] = o[nb] * al;
#pragma unroll
                for (int r = 0; r < 4; r++) {
                    float p = __builtin_amdgcn_exp2f(acc[nb][r] - mn);
                    o[nb] = o[nb] + p * vr[r];
                }
            }
        }
    }

    // merge the 4 per-quad partial softmaxes (once per kernel)
#pragma unroll
    for (int nb = 0; nb < 4; nb++) {
        float mq = mr[nb];
        float ma = fmaxf(mq, __shfl_xor(mq, 16, 64));
        ma = fmaxf(ma, __shfl_xor(ma, 32, 64));
        float wgt = __builtin_amdgcn_exp2f(mq - ma);
        floatx4 ow = o[nb] * wgt;
#pragma unroll
        for (int c = 0; c < 4; c++) {
            float v = ow[c];
            v += __shfl_xor(v, 16, 64);
            v += __shfl_xor(v, 32, 64);
            ow[c] = v;
        }
        if (quad == 0) {
            int n = n0 + nb * 16 + l15;
            size_t idx = (size_t)(chunk * NBATCH + b) * NN + n;
            Opart[idx] = make_float4(ow[0], ow[1], ow[2], ow[3]);
            Mpart[idx] = ma;
        }
    }
}

// ---------- combine the 8 m-chunk partials per (b,n) ----------
__global__ __launch_bounds__(128) void k_combine(const float4* __restrict__ Opart,
                                                 const float* __restrict__ Mpart,
                                                 float* __restrict__ out) {
    int idx = blockIdx.x * 128 + threadIdx.x;      // b*NN + n
    int b = idx >> 12, n = idx & (NN - 1);
    float mstar = -__builtin_inff();
#pragma unroll
    for (int j = 0; j < NCHUNK; j++)
        mstar = fmaxf(mstar, Mpart[(size_t)(j * NBATCH + b) * NN + n]);
    float o0 = 0.f, o1 = 0.f, o2 = 0.f, l = 0.f;
#pragma unroll
    for (int j = 0; j < NCHUNK; j++) {
        size_t id = (size_t)(j * NBATCH + b) * NN + n;
        float w = __builtin_amdgcn_exp2f(Mpart[id] - mstar);
        float4 P = Opart[id];
        o0 = fmaf(w, P.x, o0); o1 = fmaf(w, P.y, o1);
        o2 = fmaf(w, P.z, o2); l  = fmaf(w, P.w, l);
    }
    out[(size_t)(b * 3 + 0) * NN + n] = o0 / l;
    out[(size_t)(b * 3 + 1) * NN + n] = o1 / l;
    out[(size_t)(b * 3 + 2) * NN + n] = o2 / l;
}

extern "C" void kernel_launch(void* const* d_in, const int* in_sizes, int n_in,
                              void* d_out, int out_size, void* d_ws, size_t ws_size,
                              hipStream_t stream) {
    const float* tgt     = (const float*)d_in[1];
    const float* src_emb = (const float*)d_in[2];
    const float* tgt_emb = (const float*)d_in[3];
    float* out = (float*)d_out;

    char* ws = (char*)d_ws;
    // ws: Qh 8.39M | Kh 8.39M | yyS 64K | Vt 256K | Opart 2M | Mpart 512K  (~19.7 MB)
    _Float16* Qh  = (_Float16*)(ws);
    _Float16* Kh  = (_Float16*)(ws + 8388608);
    float*    yyS = (float*)   (ws + 16777216);
    float4*   Vt  = (float4*)  (ws + 16842752);
    float4*   Op  = (float4*)  (ws + 17104896);
    float*    Mp  = (float*)   (ws + 19202048);

    hipLaunchKernelGGL(k_prep,    dim3(512), dim3(256), 0, stream,
                       src_emb, tgt_emb, tgt, Qh, Kh, yyS, Vt);
    hipLaunchKernelGGL(k_flash,   dim3(512), dim3(256), 0, stream, Qh, Kh, yyS, Vt, Op, Mp);
    hipLaunchKernelGGL(k_combine, dim3(128), dim3(128), 0, stream, Op, Mp, out);
}

// Round 8
// 125.879 us; speedup vs baseline: 1.8350x; 1.0601x over previous
//
#include <hip/hip_runtime.h>

#define NBATCH 4
#define DDIM   256
#define NN     4096
#define MM     4096
#define NCHUNK 8          // m-chunks (split-K across workgroups)
#define MCHUNK 512        // m per chunk
#define MTILE  64         // m per LDS tile (8 tiles/chunk)
#define LOG2E  1.44269504088896340736f

using half8   = __attribute__((ext_vector_type(8))) _Float16;
using floatx4 = __attribute__((ext_vector_type(4))) float;

// Fragment-ordered fp16 layout (per batch): half8 at ((blk*8 + ds)*4 + quad)*16 + l15
// covers point p = blk*16 + l15, dims d = ds*32 + quad*8 .. +7.  A-frag reads and
// DMA staging are both lane-contiguous -> conflict-free LDS + coalesced global.

// ---------- prep: emb[b][d][n] fp32 -> fragment-ordered fp16; fused yy + Vt ----------
__global__ __launch_bounds__(256) void k_prep(const float* __restrict__ src_emb,
                                              const float* __restrict__ tgt_emb,
                                              const float* __restrict__ tgt,
                                              _Float16* __restrict__ Qf,
                                              _Float16* __restrict__ Kf,
                                              float* __restrict__ yyS,
                                              float4* __restrict__ Vt) {
    __shared__ float psum[4][64];
    int i = blockIdx.x;                            // 512 = xcd(8) x j(64)
    int xcd = i & 7, j = i >> 3;
    int b = xcd >> 1, nhalf = xcd & 1;             // matches flash's XCD mapping
    int tensor = j & 1, sub = j >> 1;              // sub 0..31
    int n0 = nhalf * 2048 + sub * 64;
    const float* in = tensor ? tgt_emb : src_emb;
    _Float16* outp  = tensor ? Kf : Qf;
    const float scale = tensor ? 1.0f : 2.0f * LOG2E;   // fold 2*log2e into Q
    int t = threadIdx.x, w = t >> 6, ln = t & 63;
    const float* ib = in + (size_t)b * DDIM * NN + n0 + ln;
    _Float16* ob = outp + (size_t)b * NN * 32 * 8;      // batch-b fragment space
    int blk = (n0 + ln) >> 4, l15 = ln & 15;
    float ss = 0.f;
#pragma unroll
    for (int h = 0; h < 2; h++) {                  // wave w covers ds in {w, w+4}
        int ds = w + h * 4;
#pragma unroll
        for (int oct = 0; oct < 4; oct++) {
            half8 v;
#pragma unroll
            for (int k = 0; k < 8; k++) {
                float f = ib[(size_t)(ds * 32 + oct * 8 + k) * NN];  // 256B/wave coalesced
                ss = fmaf(f, f, ss);
                v[k] = (_Float16)(f * scale);
            }
            *(half8*)(ob + ((((size_t)blk * 8 + ds) * 4 + oct) * 16 + l15) * 8) = v;
        }
    }
    if (tensor) psum[w][ln] = ss;
    __syncthreads();
    if (tensor) {
        if (t < 64) {
            float s = psum[0][t] + psum[1][t] + psum[2][t] + psum[3][t];
            yyS[b * MM + n0 + t] = s * (-LOG2E);   // pre-negated, exp2-domain
        } else if (t < 128) {
            int m = n0 + (t - 64);
            const float* tp = tgt + (size_t)b * 3 * MM + m;
            Vt[(size_t)b * MM + m] = make_float4(tp[0], tp[MM], tp[2 * MM], 1.0f);
        }
    }
}

// ---------- flash: linear-DMA dbuf K (fragment order), 1 barrier/tile ----------
__global__ __launch_bounds__(256, 2) void k_flash(const _Float16* __restrict__ Qf,
                                                  const _Float16* __restrict__ Kf,
                                                  const float* __restrict__ yyS,
                                                  const float4* __restrict__ Vt,
                                                  float4* __restrict__ Opart,
                                                  float* __restrict__ Mpart) {
    __shared__ __align__(16) _Float16 Kt[2][MTILE * DDIM];   // 2 x 32 KB, fragment order
    __shared__ floatx4 vtt[MCHUNK];                          // 8 KB {v0,v1,v2,1}
    __shared__ floatx4 yyt[MCHUNK / 4];                      // 2 KB

    int i = blockIdx.x, t = threadIdx.x;           // grid 512 = xcd(8) x j(64)
    int xcd = i & 7, j = i >> 3;
    int b = xcd >> 1, nhalf = xcd & 1;             // per-XCD K slice L2-resident
    int chunk = j & 7, ntile = nhalf * 8 + (j >> 3);

    int wave = t >> 6, lane = t & 63, quad = lane >> 4, l15 = lane & 15;
    int m0 = chunk * MCHUNK;
    int mblk0 = m0 >> 4;                           // chunk's first 16-point blk

    // linear DMA: tile mt = 32 KB contiguous in fragment space; pure memcpy to LDS
    const char* kfb = (const char*)(Kf + (size_t)b * NN * DDIM);
    auto stage = [&](int mt) {
        const char* gb = kfb + (size_t)(mblk0 + mt * 4) * 8192 + wave * 8192;
        char* lb = (char*)&Kt[mt & 1][0] + wave * 8192;
#pragma unroll
        for (int it = 0; it < 8; it++) {
            __builtin_amdgcn_global_load_lds(
                (const __attribute__((address_space(1))) uint32_t*)(const void*)
                    (gb + it * 1024 + lane * 16),
                (__attribute__((address_space(3))) uint32_t*)(void*)
                    (lb + it * 1024),
                16, 0, 0);
        }
    };

    stage(0);                                      // K-tile 0 in flight first

    // whole-chunk V + yy staged ONCE (no global loads inside the K-loop)
    {
        const float4* vb = Vt + (size_t)b * MM + m0;
        for (int r = t; r < MCHUNK; r += 256) {
            float4 g = vb[r];
            vtt[r] = (floatx4){g.x, g.y, g.z, g.w};
        }
        const floatx4* yb = (const floatx4*)(yyS + (size_t)b * MM + m0);
        if (t < MCHUNK / 4) yyt[t] = yb[t];
    }

    // persistent Q fragments: 64n x 256d per wave (128 VGPRs), fragment-order loads
    int nblk0 = ntile * 16 + wave * 4;
    const half8* qp = (const half8*)Qf + (size_t)b * NN * 32;
    half8 qf[4][8];
#pragma unroll
    for (int nb = 0; nb < 4; nb++)
#pragma unroll
        for (int ds = 0; ds < 8; ds++)
            qf[nb][ds] = qp[(((size_t)(nblk0 + nb) * 8 + ds) * 4 + quad) * 16 + l15];

    const floatx4 z4 = {0.f, 0.f, 0.f, 0.f};
    floatx4 o[4] = {z4, z4, z4, z4};               // per-quad partial {o0,o1,o2,denom}
    float mr[4];
#pragma unroll
    for (int nb = 0; nb < 4; nb++) mr[nb] = -__builtin_inff();

    for (int mt = 0; mt < MCHUNK / MTILE; mt++) {
        __syncthreads();                           // drains DMA(mt) (issued one tile ago)
        if (mt + 1 < MCHUNK / MTILE) stage(mt + 1);     // prefetch flies over this tile

        const char* Kb = (const char*)&Kt[mt & 1][0];
#pragma unroll
        for (int mb = 0; mb < 4; mb++) {           // 16-m block; quad owns m=..+quad*4+r
            // A-frags: base + lane*16 -> lane-contiguous ds_read_b128 (conflict-free)
            const char* rb = Kb + mb * 8192 + lane * 16;
            half8 a[8];
#pragma unroll
            for (int ds = 0; ds < 8; ds++) a[ds] = *(const half8*)(rb + ds * 1024);

            floatx4 acc[4] = {z4, z4, z4, z4};
#pragma unroll
            for (int ds = 0; ds < 8; ds++)
#pragma unroll
                for (int nb = 0; nb < 4; nb++)
                    acc[nb] = __builtin_amdgcn_mfma_f32_16x16x32_f16(a[ds], qf[nb][ds], acc[nb], 0, 0, 0);

            // per-quad online softmax (exp2 domain) + PV
            floatx4 yv = yyt[mt * 16 + mb * 4 + quad];
            floatx4 vr[4];
#pragma unroll
            for (int r = 0; r < 4; r++) vr[r] = vtt[mt * MTILE + mb * 16 + quad * 4 + r];
#pragma unroll
            for (int nb = 0; nb < 4; nb++) {
                acc[nb] = acc[nb] + yv;
                float tm = fmaxf(fmaxf(acc[nb][0], acc[nb][1]), fmaxf(acc[nb][2], acc[nb][3]));
                float mn = fmaxf(mr[nb], tm);
                float al = __builtin_amdgcn_exp2f(mr[nb] - mn);
                mr[nb] = mn;
                o[nb] = o[nb] * al;
#pragma unroll
                for (int r = 0; r < 4; r++) {
                    float p = __builtin_amdgcn_exp2f(acc[nb][r] - mn);
                    o[nb] = o[nb] + p * vr[r];
                }
            }
        }
    }

    // merge the 4 per-quad partial softmaxes (once per kernel)
#pragma unroll
    for (int nb = 0; nb < 4; nb++) {
        float mq = mr[nb];
        float ma = fmaxf(mq, __shfl_xor(mq, 16, 64));
        ma = fmaxf(ma, __shfl_xor(ma, 32, 64));
        float wgt = __builtin_amdgcn_exp2f(mq - ma);
        floatx4 ow = o[nb] * wgt;
#pragma unroll
        for (int c = 0; c < 4; c++) {
            float v = ow[c];
            v += __shfl_xor(v, 16, 64);
            v += __shfl_xor(v, 32, 64);
            ow[c] = v;
        }
        if (quad == 0) {
            int n = (nblk0 + nb) * 16 + l15;
            size_t idx = (size_t)(chunk * NBATCH + b) * NN + n;
            Opart[idx] = make_float4(ow[0], ow[1], ow[2], ow[3]);
            Mpart[idx] = ma;
        }
    }
}

// ---------- combine the 8 m-chunk partials per (b,n) ----------
__global__ __launch_bounds__(128) void k_combine(const float4* __restrict__ Opart,
                                                 const float* __restrict__ Mpart,
                                                 float* __restrict__ out) {
    int idx = blockIdx.x * 128 + threadIdx.x;      // b*NN + n
    int b = idx >> 12, n = idx & (NN - 1);
    float mstar = -__builtin_inff();
#pragma unroll
    for (int j = 0; j < NCHUNK; j++)
        mstar = fmaxf(mstar, Mpart[(size_t)(j * NBATCH + b) * NN + n]);
    float o0 = 0.f, o1 = 0.f, o2 = 0.f, l = 0.f;
#pragma unroll
    for (int j = 0; j < NCHUNK; j++) {
        size_t id = (size_t)(j * NBATCH + b) * NN + n;
        float w = __builtin_amdgcn_exp2f(Mpart[id] - mstar);
        float4 P = Opart[id];
        o0 = fmaf(w, P.x, o0); o1 = fmaf(w, P.y, o1);
        o2 = fmaf(w, P.z, o2); l  = fmaf(w, P.w, l);
    }
    out[(size_t)(b * 3 + 0) * NN + n] = o0 / l;
    out[(size_t)(b * 3 + 1) * NN + n] = o1 / l;
    out[(size_t)(b * 3 + 2) * NN + n] = o2 / l;
}

extern "C" void kernel_launch(void* const* d_in, const int* in_sizes, int n_in,
                              void* d_out, int out_size, void* d_ws, size_t ws_size,
                              hipStream_t stream) {
    const float* tgt     = (const float*)d_in[1];
    const float* src_emb = (const float*)d_in[2];
    const float* tgt_emb = (const float*)d_in[3];
    float* out = (float*)d_out;

    char* ws = (char*)d_ws;
    // ws: Qf 8.39M | Kf 8.39M | yyS 64K | Vt 256K | Opart 2M | Mpart 512K  (~19.7 MB)
    _Float16* Qf  = (_Float16*)(ws);
    _Float16* Kf  = (_Float16*)(ws + 8388608);
    float*    yyS = (float*)   (ws + 16777216);
    float4*   Vt  = (float4*)  (ws + 16842752);
    float4*   Op  = (float4*)  (ws + 17104896);
    float*    Mp  = (float*)   (ws + 19202048);

    hipLaunchKernelGGL(k_prep,    dim3(512), dim3(256), 0, stream,
                       src_emb, tgt_emb, tgt, Qf, Kf, yyS, Vt);
    hipLaunchKernelGGL(k_flash,   dim3(512), dim3(256), 0, stream, Qf, Kf, yyS, Vt, Op, Mp);
    hipLaunchKernelGGL(k_combine, dim3(128), dim3(128), 0, stream, Op, Mp, out);
}